// Round 1
// baseline (63.313 us; speedup 1.0000x reference)
//
#include <hip/hip_runtime.h>

#define HADN 4096
#define NFEAT 2048
#define ROWS_PER_BLOCK 4

// out-bit <- in-axis mapping of one reference "fwht" (derived by axis tracking):
// bit0<-a6, bit1<-H(a3), bit2<-a7, bit3<-a0, bit4<-a8, bit5<-H(a4),
// bit6<-a9, bit7<-a2, bit8<-a10, bit9<-H(a5), bit10<-a11, bit11<-H(a1)
__device__ __host__ __forceinline__ int pi_map(int q) {
  return  (((q >> 3) & 1))
        | (((q >> 11) & 1) << 1)
        | (((q >> 7) & 1) << 2)
        | (((q >> 1) & 1) << 3)
        | (((q >> 5) & 1) << 4)
        | (((q >> 9) & 1) << 5)
        | (((q >> 0) & 1) << 6)
        | (((q >> 2) & 1) << 7)
        | (((q >> 4) & 1) << 8)
        | (((q >> 6) & 1) << 9)
        | (((q >> 8) & 1) << 10)
        | (((q >> 10) & 1) << 11);
}

__device__ __host__ __forceinline__ int pi_inv_map(int p) {
  return  (((p >> 6) & 1))
        | (((p >> 3) & 1) << 1)
        | (((p >> 7) & 1) << 2)
        | (((p >> 0) & 1) << 3)
        | (((p >> 8) & 1) << 4)
        | (((p >> 4) & 1) << 5)
        | (((p >> 9) & 1) << 6)
        | (((p >> 2) & 1) << 7)
        | (((p >> 10) & 1) << 8)
        | (((p >> 5) & 1) << 9)
        | (((p >> 11) & 1) << 10)
        | (((p >> 1) & 1) << 11);
}

// LDS bank swizzle: XOR bits {6,7,8}^{9,10,11} into bits {2,3,4}.
// Keeps bits 0..1 intact -> float4 stays contiguous & 16B aligned.
__device__ __forceinline__ int swz(int p) {
  return p ^ ((((p >> 6) ^ (p >> 9)) & 7) << 2);
}

template <int BIT>
__device__ __forceinline__ void bfly(float* r) {
#pragma unroll
  for (int e = 0; e < 64; ++e) {
    if ((e & BIT) == 0) {
      const int f = e | BIT;
      const float a = r[e], b = r[f];
      r[e] = a + b;
      r[f] = a - b;
    }
  }
}

__global__ __launch_bounds__(256) void srf_setup(
    const float* __restrict__ D2, const float* __restrict__ D3,
    const int* __restrict__ perm,
    float* __restrict__ D2p, float* __restrict__ d3g, int* __restrict__ gidx) {
  const int i = blockIdx.x * 256 + threadIdx.x;
  if (i < HADN) {
    // w[q] = D2[q] * z1[pi(q)]  ->  in z-space: multiplier at p is D2[pi^-1(p)].
    // Fold the 1/4 normalization of fwht #1 here.
    D2p[i] = 0.25f * D2[pi_inv_map(i)];
  }
  if (i < NFEAT) {
    const int j = perm[i];
    // y2[j] = Vtilde[pi(pi(j))]; fold LDS swizzle into the stored index.
    gidx[i] = swz(pi_map(pi_map(j)));
    // Fold D3 gather and the 1/4 normalization of fwht #2.
    d3g[i] = 0.25f * D3[j];
  }
}

__global__ __launch_bounds__(256) void srf_main(
    const float* __restrict__ x, const float* __restrict__ D1,
    const float* __restrict__ D2p, const float* __restrict__ d3g,
    const int* __restrict__ gidx, const float* __restrict__ bias,
    float* __restrict__ out) {
  __shared__ float lds[ROWS_PER_BLOCK][HADN];
  const int tid = threadIdx.x;
  const long r0 = (long)blockIdx.x * ROWS_PER_BLOCK;

  // ---- Stage 1: coalesced global load, x*D1, swizzled LDS write ----
  const float4* x4 = (const float4*)(x + r0 * HADN);
#pragma unroll
  for (int k = 0; k < 16; ++k) {
    const int c4 = k * 256 + tid;      // float4 index within the 4-row chunk
    float4 v = x4[c4];
    const int c = c4 * 4;
    const int row = c >> 12;
    const int p = c & (HADN - 1);
    const float4 d = *(const float4*)(D1 + p);
    v.x *= d.x; v.y *= d.y; v.z *= d.z; v.w *= d.w;
    *(float4*)(&lds[row][swz(p)]) = v;
  }
  __syncthreads();

  // ---- Stage 2: per-lane 64-element register block; all butterflies local ----
  {
    const int w = tid >> 6;            // wave -> row
    const int l = tid & 63;            // lane's fixed bits {2,6,7,9,10,11}
    float* L = &lds[w][0];
    const int base = ((l & 1) << 2) | (((l >> 1) & 1) << 6) | (((l >> 2) & 1) << 7)
                   | (((l >> 3) & 1) << 9) | (((l >> 4) & 1) << 10) | (((l >> 5) & 1) << 11);
    float r[64];
    int paddr[16];
#pragma unroll
    for (int g = 0; g < 16; ++g) {     // g bits -> p bits {3,4,5,8}; e bits {0,1} -> p bits {0,1}
      const int p = base | ((g & 1) << 3) | (((g >> 1) & 1) << 4)
                         | (((g >> 2) & 1) << 5) | (((g >> 3) & 1) << 8);
      paddr[g] = p;
      const float4 v = *(const float4*)(L + swz(p));
      r[g * 4 + 0] = v.x; r[g * 4 + 1] = v.y; r[g * 4 + 2] = v.z; r[g * 4 + 3] = v.w;
    }
    // fwht #1: Hadamard on p-bits {1,3,4,5} = e-bits {1,2,3,4}
    bfly<2>(r); bfly<4>(r); bfly<8>(r); bfly<16>(r);
    // elementwise D2 (permuted into z-space) + 1/4 scale
#pragma unroll
    for (int g = 0; g < 16; ++g) {
      const float4 d = *(const float4*)(D2p + paddr[g]);
      r[g * 4 + 0] *= d.x; r[g * 4 + 1] *= d.y; r[g * 4 + 2] *= d.z; r[g * 4 + 3] *= d.w;
    }
    // fwht #2 in z-space: Hadamard on p-bits {0,3,4,8} = e-bits {0,2,3,5}
    bfly<1>(r); bfly<4>(r); bfly<8>(r); bfly<32>(r);
#pragma unroll
    for (int g = 0; g < 16; ++g) {
      const float4 v = make_float4(r[g * 4 + 0], r[g * 4 + 1], r[g * 4 + 2], r[g * 4 + 3]);
      *(float4*)(L + swz(paddr[g])) = v;
    }
  }
  __syncthreads();

  // ---- Stage 3: permuted gather, cos epilogue, coalesced float4 store ----
#pragma unroll
  for (int j = 0; j < 8; ++j) {
    const int idx = j * 256 + tid;     // 0..2047 float4 outputs (4 rows x 512)
    const int row = idx >> 9;
    const int o = (idx & 511) * 4;
    const int4 gi = *(const int4*)(gidx + o);
    const float4 dg = *(const float4*)(d3g + o);
    const float4 bz = *(const float4*)(bias + o);
    float4 res;
    res.x = 0.03125f * cosf(lds[row][gi.x] * dg.x + bz.x);
    res.y = 0.03125f * cosf(lds[row][gi.y] * dg.y + bz.y);
    res.z = 0.03125f * cosf(lds[row][gi.z] * dg.z + bz.z);
    res.w = 0.03125f * cosf(lds[row][gi.w] * dg.w + bz.w);
    *(float4*)(out + (r0 + row) * NFEAT + o) = res;
  }
}

extern "C" void kernel_launch(void* const* d_in, const int* in_sizes, int n_in,
                              void* d_out, int out_size, void* d_ws, size_t ws_size,
                              hipStream_t stream) {
  const float* x    = (const float*)d_in[0];
  const float* D1   = (const float*)d_in[1];
  const float* D2   = (const float*)d_in[2];
  const float* D3   = (const float*)d_in[3];
  const float* bias = (const float*)d_in[4];
  const int*   perm = (const int*)d_in[5];
  float* out = (float*)d_out;

  float* D2p = (float*)d_ws;           // 4096 f32
  float* d3g = D2p + HADN;             // 2048 f32
  int*   gidx = (int*)(d3g + NFEAT);   // 2048 i32  (32 KB total)

  srf_setup<<<16, 256, 0, stream>>>(D2, D3, perm, D2p, d3g, gidx);
  srf_main<<<8192 / ROWS_PER_BLOCK, 256, 0, stream>>>(x, D1, D2p, d3g, gidx, bias, out);
}

// Round 2
// 46.411 us; speedup vs baseline: 1.3642x; 1.3642x over previous
//
#include <hip/hip_runtime.h>

#define HADN 4096
#define NFEAT 2048

// out-bit <- in-axis mapping of one reference "fwht" (derived by axis tracking):
// bit0<-a6, bit1<-H(a3), bit2<-a7, bit3<-a0, bit4<-a8, bit5<-H(a4),
// bit6<-a9, bit7<-a2, bit8<-a10, bit9<-H(a5), bit10<-a11, bit11<-H(a1)
__device__ __host__ __forceinline__ int pi_map(int q) {
  return  (((q >> 3) & 1))
        | (((q >> 11) & 1) << 1)
        | (((q >> 7) & 1) << 2)
        | (((q >> 1) & 1) << 3)
        | (((q >> 5) & 1) << 4)
        | (((q >> 9) & 1) << 5)
        | (((q >> 0) & 1) << 6)
        | (((q >> 2) & 1) << 7)
        | (((q >> 4) & 1) << 8)
        | (((q >> 6) & 1) << 9)
        | (((q >> 8) & 1) << 10)
        | (((q >> 10) & 1) << 11);
}

__device__ __host__ __forceinline__ int pi_inv_map(int p) {
  return  (((p >> 6) & 1))
        | (((p >> 3) & 1) << 1)
        | (((p >> 7) & 1) << 2)
        | (((p >> 0) & 1) << 3)
        | (((p >> 8) & 1) << 4)
        | (((p >> 4) & 1) << 5)
        | (((p >> 9) & 1) << 6)
        | (((p >> 2) & 1) << 7)
        | (((p >> 10) & 1) << 8)
        | (((p >> 5) & 1) << 9)
        | (((p >> 11) & 1) << 10)
        | (((p >> 1) & 1) << 11);
}

// LDS bank swizzle: XOR bits {6,7,8}^{9,10,11} into bits {2,3,4}.
// Keeps bits 0..1 intact -> float4 stays contiguous & 16B aligned.
__device__ __forceinline__ int swz(int p) {
  return p ^ ((((p >> 6) ^ (p >> 9)) & 7) << 2);
}

template <int BIT>
__device__ __forceinline__ void bfly(float* r) {
#pragma unroll
  for (int e = 0; e < 16; ++e) {
    if ((e & BIT) == 0) {
      const int f = e | BIT;
      const float a = r[e], b = r[f];
      r[e] = a + b;
      r[f] = a - b;
    }
  }
}

// Butterfly across lanes differing in lane-bit `mask`; `upper` = this lane has
// the bit set (gets a-b where a is the bit-clear partner).
__device__ __forceinline__ void shfl_bfly(float* r, int mask, bool upper) {
#pragma unroll
  for (int e = 0; e < 16; ++e) {
    const float v = __shfl_xor(r[e], mask, 64);
    r[e] = upper ? (v - r[e]) : (r[e] + v);
  }
}

__global__ __launch_bounds__(256) void srf_setup(
    const float* __restrict__ D2, const float* __restrict__ D3,
    const int* __restrict__ perm,
    float* __restrict__ D2p, float* __restrict__ d3g, int* __restrict__ gidx) {
  const int i = blockIdx.x * 256 + threadIdx.x;
  if (i < HADN) {
    // In z-space the D2 multiplier at p is D2[pi^-1(p)]; fold fwht#1's 1/4.
    D2p[i] = 0.25f * D2[pi_inv_map(i)];
  }
  if (i < NFEAT) {
    const int j = perm[i];
    // Output o reads Vtilde[pi(pi(perm[o]))]; fold the LDS swizzle in.
    gidx[i] = swz(pi_map(pi_map(j)));
    // Fold D3 gather and fwht#2's 1/4.
    d3g[i] = 0.25f * D3[j];
  }
}

__global__ __launch_bounds__(256) void srf_main(
    const float* __restrict__ x, const float* __restrict__ D1,
    const float* __restrict__ D2p, const float* __restrict__ d3g,
    const int* __restrict__ gidx, const float* __restrict__ bias,
    float* __restrict__ out) {
  __shared__ float lds[HADN];           // 16 KiB -> 8 blocks/CU co-resident
  const int tid = threadIdx.x;
  const long row = blockIdx.x;

  // ---- Stage 1: coalesced row load, x*D1, swizzled LDS write ----
  const float4* x4 = (const float4*)(x + row * HADN);
#pragma unroll
  for (int k = 0; k < 4; ++k) {
    const int c4 = k * 256 + tid;       // float4 index within the row
    float4 v = x4[c4];
    const int p = c4 * 4;
    const float4 d = *(const float4*)(D1 + p);
    v.x *= d.x; v.y *= d.y; v.z *= d.z; v.w *= d.w;
    *(float4*)(&lds[swz(p)]) = v;
  }
  __syncthreads();

  // ---- Stage 2: 16 elems/lane; butterflies on p-bits {0,1,3,4} local,
  //      p-bit5 and p-bit8 via cross-lane shfl_xor ----
  {
    const int l = tid & 63;             // lane bits -> p-bits {2,5,6,7,8,9}
    const int w = tid >> 6;             // wave-in-row -> p-bits {10,11}
    const int base = ((l & 1) << 2) | (((l >> 1) & 1) << 5) | (((l >> 2) & 1) << 6)
                   | (((l >> 3) & 1) << 7) | (((l >> 4) & 1) << 8) | (((l >> 5) & 1) << 9)
                   | (w << 10);
    float r[16];
#pragma unroll
    for (int g = 0; g < 4; ++g) {       // g bits -> p-bits {3,4}
      const int p = base | ((g & 1) << 3) | (((g >> 1) & 1) << 4);
      const float4 v = *(const float4*)(&lds[swz(p)]);
      r[g * 4 + 0] = v.x; r[g * 4 + 1] = v.y; r[g * 4 + 2] = v.z; r[g * 4 + 3] = v.w;
    }
    // fwht #1: Hadamard on p-bits {1,3,4,5}: e-bits {1,2,3} + lane-bit1
    bfly<2>(r); bfly<4>(r); bfly<8>(r);
    shfl_bfly(r, 2, (l & 2) != 0);
    // elementwise D2 (permuted into z-space) + 1/4 scale
#pragma unroll
    for (int g = 0; g < 4; ++g) {
      const int p = base | ((g & 1) << 3) | (((g >> 1) & 1) << 4);
      const float4 d = *(const float4*)(D2p + p);
      r[g * 4 + 0] *= d.x; r[g * 4 + 1] *= d.y; r[g * 4 + 2] *= d.z; r[g * 4 + 3] *= d.w;
    }
    // fwht #2 in z-space: Hadamard on p-bits {0,3,4,8}: e-bits {0,2,3} + lane-bit4
    bfly<1>(r); bfly<4>(r); bfly<8>(r);
    shfl_bfly(r, 16, (l & 16) != 0);
#pragma unroll
    for (int g = 0; g < 4; ++g) {
      const int p = base | ((g & 1) << 3) | (((g >> 1) & 1) << 4);
      const float4 v = make_float4(r[g * 4 + 0], r[g * 4 + 1], r[g * 4 + 2], r[g * 4 + 3]);
      *(float4*)(&lds[swz(p)]) = v;
    }
  }
  __syncthreads();

  // ---- Stage 3: permuted gather, cos epilogue, coalesced float4 store ----
#pragma unroll
  for (int j = 0; j < 2; ++j) {
    const int idx = j * 256 + tid;      // 0..511 float4 outputs
    const int o = idx * 4;
    const int4 gi = *(const int4*)(gidx + o);
    const float4 dg = *(const float4*)(d3g + o);
    const float4 bz = *(const float4*)(bias + o);
    float4 res;
    res.x = 0.03125f * __cosf(lds[gi.x] * dg.x + bz.x);
    res.y = 0.03125f * __cosf(lds[gi.y] * dg.y + bz.y);
    res.z = 0.03125f * __cosf(lds[gi.z] * dg.z + bz.z);
    res.w = 0.03125f * __cosf(lds[gi.w] * dg.w + bz.w);
    *(float4*)(out + row * NFEAT + o) = res;
  }
}

extern "C" void kernel_launch(void* const* d_in, const int* in_sizes, int n_in,
                              void* d_out, int out_size, void* d_ws, size_t ws_size,
                              hipStream_t stream) {
  const float* x    = (const float*)d_in[0];
  const float* D1   = (const float*)d_in[1];
  const float* D2   = (const float*)d_in[2];
  const float* D3   = (const float*)d_in[3];
  const float* bias = (const float*)d_in[4];
  const int*   perm = (const int*)d_in[5];
  float* out = (float*)d_out;

  float* D2p = (float*)d_ws;           // 4096 f32
  float* d3g = D2p + HADN;             // 2048 f32
  int*   gidx = (int*)(d3g + NFEAT);   // 2048 i32  (32 KB total)

  srf_setup<<<16, 256, 0, stream>>>(D2, D3, perm, D2p, d3g, gidx);
  srf_main<<<8192, 256, 0, stream>>>(x, D1, D2p, d3g, gidx, bias, out);
}

// Round 4
// 42.540 us; speedup vs baseline: 1.4883x; 1.0910x over previous
//
#include <hip/hip_runtime.h>

#define HADN 4096
#define NFEAT 2048

typedef float floatx4 __attribute__((ext_vector_type(4)));

// out-bit <- in-axis mapping of one reference "fwht" (derived by axis tracking):
// bit0<-a6, bit1<-H(a3), bit2<-a7, bit3<-a0, bit4<-a8, bit5<-H(a4),
// bit6<-a9, bit7<-a2, bit8<-a10, bit9<-H(a5), bit10<-a11, bit11<-H(a1)
__device__ __host__ __forceinline__ int pi_map(int q) {
  return  (((q >> 3) & 1))
        | (((q >> 11) & 1) << 1)
        | (((q >> 7) & 1) << 2)
        | (((q >> 1) & 1) << 3)
        | (((q >> 5) & 1) << 4)
        | (((q >> 9) & 1) << 5)
        | (((q >> 0) & 1) << 6)
        | (((q >> 2) & 1) << 7)
        | (((q >> 4) & 1) << 8)
        | (((q >> 6) & 1) << 9)
        | (((q >> 8) & 1) << 10)
        | (((q >> 10) & 1) << 11);
}

__device__ __host__ __forceinline__ int pi_inv_map(int p) {
  return  (((p >> 6) & 1))
        | (((p >> 3) & 1) << 1)
        | (((p >> 7) & 1) << 2)
        | (((p >> 0) & 1) << 3)
        | (((p >> 8) & 1) << 4)
        | (((p >> 4) & 1) << 5)
        | (((p >> 9) & 1) << 6)
        | (((p >> 2) & 1) << 7)
        | (((p >> 10) & 1) << 8)
        | (((p >> 5) & 1) << 9)
        | (((p >> 11) & 1) << 10)
        | (((p >> 1) & 1) << 11);
}

// LDS bank swizzle: XOR bits {6,7,8}^{9,10,11} into bits {2,3,4}.
// Keeps bits 0..1 intact -> float4 stays contiguous & 16B aligned.
__device__ __forceinline__ int swz(int p) {
  return p ^ ((((p >> 6) ^ (p >> 9)) & 7) << 2);
}

template <int BIT>
__device__ __forceinline__ void bfly(float* r) {
#pragma unroll
  for (int e = 0; e < 16; ++e) {
    if ((e & BIT) == 0) {
      const int f = e | BIT;
      const float a = r[e], b = r[f];
      r[e] = a + b;
      r[f] = a - b;
    }
  }
}

// Cross-lane butterfly via DPP quad-perm (VALU, not DS pipe).
// CTRL=0xB1 -> lane^1, CTRL=0x4E -> lane^2. `upper` lane computes partner-own.
template <int CTRL>
__device__ __forceinline__ void dpp_bfly(float* r, bool upper) {
  const unsigned sm = upper ? 0x80000000u : 0u;
#pragma unroll
  for (int e = 0; e < 16; ++e) {
    const int pv = __builtin_amdgcn_update_dpp(
        0, __float_as_int(r[e]), CTRL, 0xF, 0xF, true);
    r[e] = __int_as_float(pv) + __int_as_float(__float_as_int(r[e]) ^ sm);
  }
}

__global__ __launch_bounds__(256) void srf_setup(
    const float* __restrict__ D2, const float* __restrict__ D3,
    const int* __restrict__ perm,
    unsigned* __restrict__ D2sgn, float* __restrict__ d3g,
    int* __restrict__ gidx) {
  const int i = blockIdx.x * 256 + threadIdx.x;
  if (i < HADN / 32) {
    // Packed signs of D2[pi_inv(p)]: word p>>5, bit p&31.
    unsigned wrd = 0;
    for (int j = 0; j < 32; ++j) {
      const int p = i * 32 + j;
      wrd |= (__float_as_uint(D2[pi_inv_map(p)]) >> 31) << j;
    }
    D2sgn[i] = wrd;
  }
  if (i < NFEAT) {
    const int j = perm[i];
    // Output o reads Vtilde[pi(pi(perm[o]))]; fold the LDS swizzle in.
    gidx[i] = swz(pi_map(pi_map(j)));
    // Fold D3 gather and BOTH fwht 1/4 normalizations (D2 is sign-only now).
    d3g[i] = 0.0625f * D3[j];
  }
}

__global__ __launch_bounds__(256) void srf_main(
    const float* __restrict__ x, const float* __restrict__ D1,
    const unsigned* __restrict__ D2sgn, const float* __restrict__ d3g,
    const int* __restrict__ gidx, const float* __restrict__ bias,
    float* __restrict__ out) {
  __shared__ float lds[HADN];           // 16 KiB -> 8 blocks/CU co-resident
  const int tid = threadIdx.x;
  const long row = blockIdx.x;

  // ---- Stage 1: coalesced row load, x*D1, swizzled LDS write ----
  const float4* x4 = (const float4*)(x + row * HADN);
#pragma unroll
  for (int k = 0; k < 4; ++k) {
    const int c4 = k * 256 + tid;       // float4 index within the row
    float4 v = x4[c4];
    const int p = c4 * 4;
    const float4 d = *(const float4*)(D1 + p);
    v.x *= d.x; v.y *= d.y; v.z *= d.z; v.w *= d.w;
    *(float4*)(&lds[swz(p)]) = v;
  }
  __syncthreads();

  // ---- Stage 2: 16 elems/lane; p-bits {0,1,3,4} thread-local,
  //      p-bit5 on lane-bit0 (DPP xor1), p-bit8 on lane-bit1 (DPP xor2) ----
  {
    const int l = tid & 63;
    const int w = tid >> 6;             // wave-in-row -> p-bits {10,11}
    const int base = (((l >> 2) & 1) << 2) | ((l & 1) << 5) | (((l >> 3) & 1) << 6)
                   | (((l >> 4) & 1) << 7) | (((l >> 1) & 1) << 8)
                   | (((l >> 5) & 1) << 9) | (w << 10);
    float r[16];
#pragma unroll
    for (int g = 0; g < 4; ++g) {       // g bits -> p-bits {3,4}
      const int p = base | ((g & 1) << 3) | (((g >> 1) & 1) << 4);
      const float4 v = *(const float4*)(&lds[swz(p)]);
      r[g * 4 + 0] = v.x; r[g * 4 + 1] = v.y; r[g * 4 + 2] = v.z; r[g * 4 + 3] = v.w;
    }
    // fwht #1: Hadamard on p-bits {1,3,4,5}: e-bits {1,2,3} + lane-bit0
    bfly<2>(r); bfly<4>(r); bfly<8>(r);
    dpp_bfly<0xB1>(r, (l & 1) != 0);
    // elementwise D2 signs (permuted into z-space), packed 1 word/lane
    {
      const unsigned sw2 = D2sgn[base >> 5] >> (base & 4);
#pragma unroll
      for (int e = 0; e < 16; ++e) {
        const int pos = (e & 3) | ((e & 12) << 1);   // e0,e1 -> bits 0,1; e2,e3 -> bits 3,4
        const unsigned m = (sw2 >> pos) << 31;
        r[e] = __int_as_float(__float_as_int(r[e]) ^ m);
      }
    }
    // fwht #2: Hadamard on p-bits {0,3,4,8}: e-bits {0,2,3} + lane-bit1
    bfly<1>(r); bfly<4>(r); bfly<8>(r);
    dpp_bfly<0x4E>(r, (l & 2) != 0);
#pragma unroll
    for (int g = 0; g < 4; ++g) {
      const int p = base | ((g & 1) << 3) | (((g >> 1) & 1) << 4);
      const float4 v = make_float4(r[g * 4 + 0], r[g * 4 + 1], r[g * 4 + 2], r[g * 4 + 3]);
      *(float4*)(&lds[swz(p)]) = v;
    }
  }
  __syncthreads();

  // ---- Stage 3: permuted gather, cos epilogue, coalesced nt float4 store ----
#pragma unroll
  for (int j = 0; j < 2; ++j) {
    const int idx = j * 256 + tid;      // 0..511 float4 outputs
    const int o = idx * 4;
    const int4 gi = *(const int4*)(gidx + o);
    const float4 dg = *(const float4*)(d3g + o);
    const float4 bz = *(const float4*)(bias + o);
    floatx4 res;
    res.x = 0.03125f * __cosf(lds[gi.x] * dg.x + bz.x);
    res.y = 0.03125f * __cosf(lds[gi.y] * dg.y + bz.y);
    res.z = 0.03125f * __cosf(lds[gi.z] * dg.z + bz.z);
    res.w = 0.03125f * __cosf(lds[gi.w] * dg.w + bz.w);
    __builtin_nontemporal_store(res, (floatx4*)(out + row * NFEAT + o));
  }
}

extern "C" void kernel_launch(void* const* d_in, const int* in_sizes, int n_in,
                              void* d_out, int out_size, void* d_ws, size_t ws_size,
                              hipStream_t stream) {
  const float* x    = (const float*)d_in[0];
  const float* D1   = (const float*)d_in[1];
  const float* D2   = (const float*)d_in[2];
  const float* D3   = (const float*)d_in[3];
  const float* bias = (const float*)d_in[4];
  const int*   perm = (const int*)d_in[5];
  float* out = (float*)d_out;

  unsigned* D2sgn = (unsigned*)d_ws;       // 128 u32
  float*    d3g   = (float*)(D2sgn + 128); // 2048 f32
  int*      gidx  = (int*)(d3g + NFEAT);   // 2048 i32

  srf_setup<<<8, 256, 0, stream>>>(D2, D3, perm, D2sgn, d3g, gidx);
  srf_main<<<8192, 256, 0, stream>>>(x, D1, D2sgn, d3g, gidx, bias, out);
}